// Round 4
// baseline (1809.002 us; speedup 1.0000x reference)
//
#include <hip/hip_runtime.h>

#define HH 64
#define TT 2048
#define BB 256
#define YSZ (BB*TT)   // y elements before hT in d_out

__device__ __forceinline__ float sigmoid_f(float v) {
    return 1.0f / (1.0f + __expf(-v));
}
__device__ __forceinline__ float tanh_f(float v) {
    return 1.0f - 2.0f / (1.0f + __expf(2.0f * v));
}

// Force a value to be an opaque register def: defeats invariant-load
// rematerialization (rounds 2-3: compiler sank weight loads into the loop,
// VGPR_Count=88 < the 96 floats needed -> re-read from L1 every timestep).
#define PIN4(v) asm("" : "+v"((v).x), "+v"((v).y), "+v"((v).z), "+v"((v).w))
#define PIN1(s) asm("" : "+v"(s))

// 512 threads = 8 waves (2/SIMD). Dot products k-split across thread pairs
// (half = tid>>8). 24 float4 weight slices per thread, pinned in VGPRs.
__global__ __launch_bounds__(512, 1)
void gru_fused(const float* __restrict__ x,      // [B,T,1]
               const float* __restrict__ h0in,   // [2,B,H]
               const float* __restrict__ W_ih0,  // [192,1]
               const float* __restrict__ W_hh0,  // [192,64]
               const float* __restrict__ b_ih0,  // [192]
               const float* __restrict__ b_hh0,  // [192]
               const float* __restrict__ W_ih1,  // [192,64]
               const float* __restrict__ W_hh1,  // [192,64]
               const float* __restrict__ b_ih1,  // [192]
               const float* __restrict__ b_hh1,  // [192]
               const float* __restrict__ Wh1,    // [64,64]
               const float* __restrict__ bh1,    // [64]
               const float* __restrict__ Wh2,    // [1,64]
               const float* __restrict__ bh2,    // [1]
               float* __restrict__ out)          // y [B*T] ++ hT [2,B,H]
{
    const int b    = blockIdx.x;
    const int tid  = threadIdx.x;
    const int t    = tid & 255;   // role id within half-group
    const int half = tid >> 8;    // k-half: 0 -> k in [0,32), 1 -> [32,64)
    const int ko   = half << 5;

    __shared__ __align__(16) float h0_lds[HH];
    __shared__ __align__(16) float h1_lds[HH];
    __shared__ __align__(16) float part[2 * 192 * 4]; // float4 per (half,row): {gh0,gx1,gh1,pad}
    __shared__ __align__(16) float ph[2 * 64];        // head partials
    __shared__ __align__(16) float x_lds[TT];

    // ---- preload x row (coalesced float4), init h ----
    {
        const float4* xs = reinterpret_cast<const float4*>(x + (size_t)b * TT);
        float4*       xd = reinterpret_cast<float4*>(x_lds);
        for (int k = tid; k < TT / 4; k += 512) xd[k] = xs[k];
    }
    if (tid < HH) {
        h0_lds[tid] = h0in[           b * HH + tid];
        h1_lds[tid] = h0in[BB * HH +  b * HH + tid];
    }

    // ---- per-thread weights in NAMED registers (k-half slices) ----
    float4 wa0, wa1, wa2, wa3, wa4, wa5, wa6, wa7;
    float4 wb0, wb1, wb2, wb3, wb4, wb5, wb6, wb7;
    float4 wc0, wc1, wc2, wc3, wc4, wc5, wc6, wc7;
    float bA = 0.f, bB = 0.f, bC = 0.f;
    if (t < 192) {
        const float4* pa = reinterpret_cast<const float4*>(W_hh0 + t * HH + ko);
        const float4* pb = reinterpret_cast<const float4*>(W_ih1 + t * HH + ko);
        const float4* pc = reinterpret_cast<const float4*>(W_hh1 + t * HH + ko);
        wa0 = pa[0]; wb0 = pb[0]; wc0 = pc[0];
        wa1 = pa[1]; wb1 = pb[1]; wc1 = pc[1];
        wa2 = pa[2]; wb2 = pb[2]; wc2 = pc[2];
        wa3 = pa[3]; wb3 = pb[3]; wc3 = pc[3];
        wa4 = pa[4]; wb4 = pb[4]; wc4 = pc[4];
        wa5 = pa[5]; wb5 = pb[5]; wc5 = pc[5];
        wa6 = pa[6]; wb6 = pb[6]; wc6 = pc[6];
        wa7 = pa[7]; wb7 = pb[7]; wc7 = pc[7];
        if (half == 0) { bA = b_hh0[t]; bB = b_ih1[t]; bC = b_hh1[t]; }
    } else {
        const float4* pa = reinterpret_cast<const float4*>(Wh1 + (t - 192) * HH + ko);
        wa0 = pa[0]; wa1 = pa[1]; wa2 = pa[2]; wa3 = pa[3];
        wa4 = pa[4]; wa5 = pa[5]; wa6 = pa[6]; wa7 = pa[7];
        wb0 = wa0; wb1 = wa1; wb2 = wa2; wb3 = wa3;
        wb4 = wa4; wb5 = wa5; wb6 = wa6; wb7 = wa7;
        wc0 = wa0; wc1 = wa1; wc2 = wa2; wc3 = wa3;
        wc4 = wa4; wc5 = wa5; wc6 = wa6; wc7 = wa7;
    }
    // Pin all weight slices into VGPRs (opaque defs, no code emitted).
    PIN4(wa0); PIN4(wa1); PIN4(wa2); PIN4(wa3);
    PIN4(wa4); PIN4(wa5); PIN4(wa6); PIN4(wa7);
    PIN4(wb0); PIN4(wb1); PIN4(wb2); PIN4(wb3);
    PIN4(wb4); PIN4(wb5); PIN4(wb6); PIN4(wb7);
    PIN4(wc0); PIN4(wc1); PIN4(wc2); PIN4(wc3);
    PIN4(wc4); PIN4(wc5); PIN4(wc6); PIN4(wc7);
    PIN1(bA);  PIN1(bB);  PIN1(bC);

    float wih0_r = 0.f, wih0_z = 0.f, wih0_n = 0.f;
    float bih0_r = 0.f, bih0_z = 0.f, bih0_n = 0.f;
    if (tid >= 64 && tid < 128) {
        const int j = tid - 64;
        wih0_r = W_ih0[j];       bih0_r = b_ih0[j];
        wih0_z = W_ih0[j + 64];  bih0_z = b_ih0[j + 64];
        wih0_n = W_ih0[j + 128]; bih0_n = b_ih0[j + 128];
    }
    PIN1(wih0_r); PIN1(wih0_z); PIN1(wih0_n);
    PIN1(bih0_r); PIN1(bih0_z); PIN1(bih0_n);
    float wh2_r = 0.f, bhead = 0.f, bh2_s = 0.f;
    if (tid >= 448) {
        const int j = tid - 448;
        wh2_r = Wh2[j]; bhead = bh1[j]; bh2_s = bh2[0];
    }
    PIN1(wh2_r); PIN1(bhead); PIN1(bh2_s);

    __syncthreads();

    const float4* h0q   = reinterpret_cast<const float4*>(h0_lds + ko);
    const float4* h1q   = reinterpret_cast<const float4*>(h1_lds + ko);
    float4*       part4 = reinterpret_cast<float4*>(part);

#define GSTEP(i) { float4 u = h0q[i]; float4 v = h1q[i]; \
    a0 = fmaf(wa##i.x, u.x, a0); a1 = fmaf(wb##i.x, u.x, a1); a2 = fmaf(wc##i.x, v.x, a2); \
    a0 = fmaf(wa##i.y, u.y, a0); a1 = fmaf(wb##i.y, u.y, a1); a2 = fmaf(wc##i.y, v.y, a2); \
    a0 = fmaf(wa##i.z, u.z, a0); a1 = fmaf(wb##i.z, u.z, a1); a2 = fmaf(wc##i.z, v.z, a2); \
    a0 = fmaf(wa##i.w, u.w, a0); a1 = fmaf(wb##i.w, u.w, a1); a2 = fmaf(wc##i.w, v.w, a2); }
#define HSTEP(i) { float4 v = h1q[i]; \
    s = fmaf(wa##i.x, v.x, s); s = fmaf(wa##i.y, v.y, s); \
    s = fmaf(wa##i.z, v.z, s); s = fmaf(wa##i.w, v.w, s); }

    // Pipeline, 2 barriers/iter:
    //   A(i): partial gh0(i)=W_hh0@h0^i ; gx1(i-1)=W_ih1@h0^i ;
    //         gh1(i-1)=W_hh1@h1^(i-1) ; head partial from h1^(i-1)
    //   B(i): combine layer-1 -> h1^i ; combine layer-0 -> h0^(i+1) ; y[i-2]
    for (int i = 0; i <= TT + 1; ++i) {
        // ---------------- Phase A: partial dots (k-half) ----------------
        if (t < 192) {
            float a0 = bA, a1 = bB, a2 = bC;
            GSTEP(0) GSTEP(1) GSTEP(2) GSTEP(3)
            GSTEP(4) GSTEP(5) GSTEP(6) GSTEP(7)
            part4[half * 192 + t] = make_float4(a0, a1, a2, 0.f);  // one ds_write_b128
        } else {
            float s = 0.f;
            HSTEP(0) HSTEP(1) HSTEP(2) HSTEP(3)
            HSTEP(4) HSTEP(5) HSTEP(6) HSTEP(7)
            ph[half * 64 + (t - 192)] = s;
        }
        __syncthreads();

        // ---------------- Phase B: combines ----------------
        if (tid < 64) {
            // layer-1 combine for step (i-1)
            const int j = tid;
            float4 q0r = part4[j];       float4 q1r = part4[192 + j];
            float4 q0z = part4[j + 64];  float4 q1z = part4[192 + j + 64];
            float4 q0n = part4[j + 128]; float4 q1n = part4[192 + j + 128];
            float r = sigmoid_f(q0r.y + q1r.y + q0r.z + q1r.z);
            float z = sigmoid_f(q0z.y + q1z.y + q0z.z + q1z.z);
            float n = tanh_f(fmaf(r, q0n.z + q1n.z, q0n.y + q1n.y));
            if (i >= 1 && i <= TT) {
                float hp = h1_lds[j];
                h1_lds[j] = fmaf(z, hp - n, n);   // (1-z)*n + z*h
            }
        } else if (tid < 128) {
            // layer-0 combine for step i
            const int j  = tid - 64;
            const int xi = (i < TT) ? i : (TT - 1);
            float4 q0r = part4[j];       float4 q1r = part4[192 + j];
            float4 q0z = part4[j + 64];  float4 q1z = part4[192 + j + 64];
            float4 q0n = part4[j + 128]; float4 q1n = part4[192 + j + 128];
            float xv = x_lds[xi];
            float r = sigmoid_f(fmaf(xv, wih0_r, bih0_r) + q0r.x + q1r.x);
            float z = sigmoid_f(fmaf(xv, wih0_z, bih0_z) + q0z.x + q1z.x);
            float n = tanh_f(fmaf(r, q0n.x + q1n.x, fmaf(xv, wih0_n, bih0_n)));
            if (i < TT) {
                float hp = h0_lds[j];
                h0_lds[j] = fmaf(z, hp - n, n);
            }
        } else if (tid >= 448) {
            // head combine + reduce for y[i-2]
            const int j = tid - 448;
            float s = ph[j] + ph[64 + j] + bhead;
            float p = fmaxf(s, 0.f) * wh2_r;
            #pragma unroll
            for (int m = 1; m < 64; m <<= 1) p += __shfl_xor(p, m, 64);
            if (tid == 448 && i >= 2) out[(size_t)b * TT + (i - 2)] = p + bh2_s;
        }
        __syncthreads();
    }

    // final hidden states: hT[2,B,H]
    if (tid < HH) {
        out[YSZ +           b * HH + tid] = h0_lds[tid];
        out[YSZ + BB * HH + b * HH + tid] = h1_lds[tid];
    }
}

extern "C" void kernel_launch(void* const* d_in, const int* in_sizes, int n_in,
                              void* d_out, int out_size, void* d_ws, size_t ws_size,
                              hipStream_t stream) {
    const float* x     = (const float*)d_in[0];
    const float* h0in  = (const float*)d_in[1];
    const float* W_ih0 = (const float*)d_in[2];
    const float* W_hh0 = (const float*)d_in[3];
    const float* b_ih0 = (const float*)d_in[4];
    const float* b_hh0 = (const float*)d_in[5];
    const float* W_ih1 = (const float*)d_in[6];
    const float* W_hh1 = (const float*)d_in[7];
    const float* b_ih1 = (const float*)d_in[8];
    const float* b_hh1 = (const float*)d_in[9];
    const float* Wh1   = (const float*)d_in[10];
    const float* bh1   = (const float*)d_in[11];
    const float* Wh2   = (const float*)d_in[12];
    const float* bh2   = (const float*)d_in[13];
    float* out = (float*)d_out;

    gru_fused<<<dim3(BB), dim3(512), 0, stream>>>(
        x, h0in, W_ih0, W_hh0, b_ih0, b_hh0,
        W_ih1, W_hh1, b_ih1, b_hh1, Wh1, bh1, Wh2, bh2, out);
}

// Round 5
// 1556.079 us; speedup vs baseline: 1.1625x; 1.1625x over previous
//
#include <hip/hip_runtime.h>

#define HH 64
#define TT 2048
#define BB 256
#define YSZ (BB*TT)   // y elements before hT in d_out

__device__ __forceinline__ float sigmoid_f(float v) {
    return 1.0f / (1.0f + __expf(-v));
}
__device__ __forceinline__ float tanh_f(float v) {
    return 1.0f - 2.0f / (1.0f + __expf(2.0f * v));
}

// 1024 threads = 16 waves (4/SIMD). Dot products k-split 4 ways so each gate
// thread holds only 48 weight floats (12 float4) -- inside the ~88-128 VGPR
// envelope the allocator accepted in rounds 1-4 (it refused to hold 96-192
// floats live across the barrier loop; 48 should hoist cleanly, no PINs).
// Wave roles (wave w sits on SIMD w%4):
//   waves 0-11 : gate quarters, q = tid/192 -> each SIMD gets 3 gate waves
//   waves 12-15: head partials, one per SIMD
//   phase B    : wave0 = layer-1 combine, wave1 = layer-0 combine,
//                wave2 = head finish (SIMDs 0/1/2)
__global__ __launch_bounds__(1024, 4)
void gru_fused(const float* __restrict__ x,      // [B,T,1]
               const float* __restrict__ h0in,   // [2,B,H]
               const float* __restrict__ W_ih0,  // [192,1]
               const float* __restrict__ W_hh0,  // [192,64]
               const float* __restrict__ b_ih0,  // [192]
               const float* __restrict__ b_hh0,  // [192]
               const float* __restrict__ W_ih1,  // [192,64]
               const float* __restrict__ W_hh1,  // [192,64]
               const float* __restrict__ b_ih1,  // [192]
               const float* __restrict__ b_hh1,  // [192]
               const float* __restrict__ Wh1,    // [64,64]
               const float* __restrict__ bh1,    // [64]
               const float* __restrict__ Wh2,    // [1,64]
               const float* __restrict__ bh2,    // [1]
               float* __restrict__ out)          // y [B*T] ++ hT [2,B,H]
{
    const int b   = blockIdx.x;
    const int tid = threadIdx.x;

    __shared__ __align__(16) float  h0_lds[HH];
    __shared__ __align__(16) float  h1_lds[HH];
    __shared__ __align__(16) float4 part4s[4 * 192];  // per (quarter,row): {gh0,gx1,gh1,-}
    __shared__ __align__(16) float  ph[4 * 64];       // head partials
    __shared__ __align__(16) float  x_lds[TT];

    // ---- preload x row (coalesced float4), init h ----
    {
        const float4* xs = reinterpret_cast<const float4*>(x + (size_t)b * TT);
        float4*       xd = reinterpret_cast<float4*>(x_lds);
        if (tid < TT / 4) xd[tid] = xs[tid];
    }
    if (tid < HH) {
        h0_lds[tid] = h0in[          b * HH + tid];
        h1_lds[tid] = h0in[BB * HH + b * HH + tid];
    }

    // ---- role decode ----
    const bool is_gate = tid < 768;
    int q, t;  // gate: quarter 0-3 / row 0-191. head: quarter 0-3 / row 0-63.
    if (is_gate) { q = tid / 192; t = tid - q * 192; }
    else         { q = (tid - 768) >> 6; t = (tid - 768) & 63; }

    // ---- per-thread weight slices: 16 floats per matrix ----
    float4 wa0, wa1, wa2, wa3;   // gate: W_hh0 row slice | head: Wh1 row slice
    float4 wb0, wb1, wb2, wb3;   // gate: W_ih1 row slice
    float4 wc0, wc1, wc2, wc3;   // gate: W_hh1 row slice
    float bA = 0.f, bB = 0.f, bC = 0.f;
    if (is_gate) {
        const float4* pa = reinterpret_cast<const float4*>(W_hh0 + t * HH + q * 16);
        const float4* pb = reinterpret_cast<const float4*>(W_ih1 + t * HH + q * 16);
        const float4* pc = reinterpret_cast<const float4*>(W_hh1 + t * HH + q * 16);
        wa0 = pa[0]; wa1 = pa[1]; wa2 = pa[2]; wa3 = pa[3];
        wb0 = pb[0]; wb1 = pb[1]; wb2 = pb[2]; wb3 = pb[3];
        wc0 = pc[0]; wc1 = pc[1]; wc2 = pc[2]; wc3 = pc[3];
        if (q == 0) { bA = b_hh0[t]; bB = b_ih1[t]; bC = b_hh1[t]; }
    } else {
        const float4* pa = reinterpret_cast<const float4*>(Wh1 + t * HH + q * 16);
        wa0 = pa[0]; wa1 = pa[1]; wa2 = pa[2]; wa3 = pa[3];
        wb0 = wb1 = wb2 = wb3 = make_float4(0.f, 0.f, 0.f, 0.f);
        wc0 = wc1 = wc2 = wc3 = make_float4(0.f, 0.f, 0.f, 0.f);
    }
    // layer-0 combine consts (wave 1)
    float wih0_r = 0.f, wih0_z = 0.f, wih0_n = 0.f;
    float bih0_r = 0.f, bih0_z = 0.f, bih0_n = 0.f;
    if (tid >= 64 && tid < 128) {
        const int j = tid - 64;
        wih0_r = W_ih0[j];       bih0_r = b_ih0[j];
        wih0_z = W_ih0[j + 64];  bih0_z = b_ih0[j + 64];
        wih0_n = W_ih0[j + 128]; bih0_n = b_ih0[j + 128];
    }
    // head finish consts (wave 2)
    float wh2r = 0.f, bh1r = 0.f, bh2s = 0.f;
    if (tid >= 128 && tid < 192) {
        const int j = tid - 128;
        wh2r = Wh2[j]; bh1r = bh1[j]; bh2s = bh2[0];
    }

    __syncthreads();

    const float4* h0q = reinterpret_cast<const float4*>(h0_lds) + (q << 2);
    const float4* h1q = reinterpret_cast<const float4*>(h1_lds) + (q << 2);

#define GSTEP(i) { float4 u = h0q[i]; float4 v = h1q[i]; \
    a0 = fmaf(wa##i.x, u.x, a0); a1 = fmaf(wb##i.x, u.x, a1); a2 = fmaf(wc##i.x, v.x, a2); \
    a0 = fmaf(wa##i.y, u.y, a0); a1 = fmaf(wb##i.y, u.y, a1); a2 = fmaf(wc##i.y, v.y, a2); \
    a0 = fmaf(wa##i.z, u.z, a0); a1 = fmaf(wb##i.z, u.z, a1); a2 = fmaf(wc##i.z, v.z, a2); \
    a0 = fmaf(wa##i.w, u.w, a0); a1 = fmaf(wb##i.w, u.w, a1); a2 = fmaf(wc##i.w, v.w, a2); }
#define HSTEP(i) { float4 v = h1q[i]; \
    s = fmaf(wa##i.x, v.x, s); s = fmaf(wa##i.y, v.y, s); \
    s = fmaf(wa##i.z, v.z, s); s = fmaf(wa##i.w, v.w, s); }

    // Pipeline, 2 barriers/iter (schedule identical to rounds 1-4):
    //   A(i): partial gh0(i)=W_hh0@h0^i ; gx1(i-1)=W_ih1@h0^i ;
    //         gh1(i-1)=W_hh1@h1^(i-1) ; head partial from h1^(i-1)
    //   B(i): combine layer-1 -> h1^i ; combine layer-0 -> h0^(i+1) ; y[i-2]
    for (int i = 0; i <= TT + 1; ++i) {
        // ---------------- Phase A: quarter-partial dots ----------------
        if (is_gate) {
            float a0 = bA, a1 = bB, a2 = bC;
            GSTEP(0) GSTEP(1) GSTEP(2) GSTEP(3)
            part4s[q * 192 + t] = make_float4(a0, a1, a2, 0.f);
        } else {
            float s = 0.f;
            HSTEP(0) HSTEP(1) HSTEP(2) HSTEP(3)
            ph[q * 64 + t] = s;
        }
        __syncthreads();

        // ---------------- Phase B: combines ----------------
        if (tid < 64) {
            // layer-1 combine for step (i-1)
            const int j = tid;
            float sxr = 0.f, shr = 0.f, sxz = 0.f, shz = 0.f, sxn = 0.f, shn = 0.f;
            #pragma unroll
            for (int qq = 0; qq < 4; ++qq) {
                float4 fr = part4s[qq * 192 + j];
                float4 fz = part4s[qq * 192 + j + 64];
                float4 fn = part4s[qq * 192 + j + 128];
                sxr += fr.y; shr += fr.z;
                sxz += fz.y; shz += fz.z;
                sxn += fn.y; shn += fn.z;
            }
            float r = sigmoid_f(sxr + shr);
            float z = sigmoid_f(sxz + shz);
            float n = tanh_f(fmaf(r, shn, sxn));
            if (i >= 1 && i <= TT) {
                float hp = h1_lds[j];
                h1_lds[j] = fmaf(z, hp - n, n);   // (1-z)*n + z*h
            }
        } else if (tid < 128) {
            // layer-0 combine for step i
            const int j  = tid - 64;
            const int xi = (i < TT) ? i : (TT - 1);
            float g0 = 0.f, g1 = 0.f, g2 = 0.f;
            #pragma unroll
            for (int qq = 0; qq < 4; ++qq) {
                g0 += part4s[qq * 192 + j].x;
                g1 += part4s[qq * 192 + j + 64].x;
                g2 += part4s[qq * 192 + j + 128].x;
            }
            float xv = x_lds[xi];
            float r = sigmoid_f(fmaf(xv, wih0_r, bih0_r) + g0);
            float z = sigmoid_f(fmaf(xv, wih0_z, bih0_z) + g1);
            float n = tanh_f(fmaf(r, g2, fmaf(xv, wih0_n, bih0_n)));
            if (i < TT) {
                float hp = h0_lds[j];
                h0_lds[j] = fmaf(z, hp - n, n);
            }
        } else if (tid < 192) {
            // head finish for y[i-2]
            const int j = tid - 128;
            float s = ph[j] + ph[64 + j] + ph[128 + j] + ph[192 + j] + bh1r;
            float p = fmaxf(s, 0.f) * wh2r;
            #pragma unroll
            for (int m = 1; m < 64; m <<= 1) p += __shfl_xor(p, m, 64);
            if (tid == 128 && i >= 2) out[(size_t)b * TT + (i - 2)] = p + bh2s;
        }
        __syncthreads();
    }

    // final hidden states: hT[2,B,H]
    if (tid < HH) {
        out[YSZ +           b * HH + tid] = h0_lds[tid];
        out[YSZ + BB * HH + b * HH + tid] = h1_lds[tid];
    }
}

extern "C" void kernel_launch(void* const* d_in, const int* in_sizes, int n_in,
                              void* d_out, int out_size, void* d_ws, size_t ws_size,
                              hipStream_t stream) {
    const float* x     = (const float*)d_in[0];
    const float* h0in  = (const float*)d_in[1];
    const float* W_ih0 = (const float*)d_in[2];
    const float* W_hh0 = (const float*)d_in[3];
    const float* b_ih0 = (const float*)d_in[4];
    const float* b_hh0 = (const float*)d_in[5];
    const float* W_ih1 = (const float*)d_in[6];
    const float* W_hh1 = (const float*)d_in[7];
    const float* b_ih1 = (const float*)d_in[8];
    const float* b_hh1 = (const float*)d_in[9];
    const float* Wh1   = (const float*)d_in[10];
    const float* bh1   = (const float*)d_in[11];
    const float* Wh2   = (const float*)d_in[12];
    const float* bh2   = (const float*)d_in[13];
    float* out = (float*)d_out;

    gru_fused<<<dim3(BB), dim3(1024), 0, stream>>>(
        x, h0in, W_ih0, W_hh0, b_ih0, b_hh0,
        W_ih1, W_hh1, b_ih1, b_hh1, Wh1, bh1, Wh2, bh2, out);
}